// Round 1
// baseline (459.935 us; speedup 1.0000x reference)
//
#include <hip/hip_runtime.h>
#include <hip/hip_bf16.h>

#define BDOC 8
#define NROW 4096
#define DDIM 768
#define NT   32          // NROW / BM
#define BM   128
#define BK   64
#define CAP_E  8192
#define ROWCAP 512
#define SIM_T 0.2f

typedef __attribute__((ext_vector_type(8))) __bf16 bf16x8;
typedef __attribute__((ext_vector_type(4))) float  f32x4;

#define GLDS16(gptr, lptr) __builtin_amdgcn_global_load_lds( \
    (const __attribute__((address_space(1))) void*)(gptr),   \
    (__attribute__((address_space(3))) void*)(lptr), 16, 0, 0)

// ---------------- stage 1: row norms + bf16 normalized copy ----------------
__global__ __launch_bounds__(256)
void nrm_kernel(const float* __restrict__ emb, __hip_bfloat16* __restrict__ nrmbf) {
  int row = blockIdx.x;                       // 0 .. BDOC*NROW-1
  const float* x = emb + (size_t)row * DDIM;
  int t = threadIdx.x;
  float v0 = x[t], v1 = x[t + 256], v2 = x[t + 512];
  float ss = v0 * v0 + v1 * v1 + v2 * v2;
  #pragma unroll
  for (int o = 32; o > 0; o >>= 1) ss += __shfl_down(ss, o);
  __shared__ float wsum[4];
  if ((t & 63) == 0) wsum[t >> 6] = ss;
  __syncthreads();
  float tot = wsum[0] + wsum[1] + wsum[2] + wsum[3];
  float inv = 1.0f / fmaxf(sqrtf(tot), 1e-8f);
  __hip_bfloat16* o = nrmbf + (size_t)row * DDIM;
  o[t]       = __float2bfloat16(v0 * inv);
  o[t + 256] = __float2bfloat16(v1 * inv);
  o[t + 512] = __float2bfloat16(v2 * inv);
}

// ---------------- sparse bookkeeping ----------------
__device__ __forceinline__ void touch_row(int b, int i, float v,
    int* flags, int* rowcnt, int* rowlist, float* rowsum) {
  atomicAdd(&rowsum[b * NROW + i], v);
  if (atomicCAS(&flags[b * NROW + i], 0, (int)0x80000000) == 0) {
    int s = atomicAdd(&rowcnt[b], 1);
    if (s < ROWCAP) {
      rowlist[b * ROWCAP + s] = i;
      __threadfence();
      flags[b * NROW + i] = s + 1;
    }
  }
}

// ---------------- stage 2: Gram + threshold (MFMA bf16, upper triangle) ----
__global__ __launch_bounds__(256)
void gram_kernel(const ushort* __restrict__ nrm,
                 int* __restrict__ cnt, int* __restrict__ rowcnt,
                 int* __restrict__ entI, int* __restrict__ entJ, float* __restrict__ entV,
                 int* __restrict__ flags, int* __restrict__ rowlist,
                 float* __restrict__ rowsum) {
  __shared__ ushort lA[BM * BK];
  __shared__ ushort lB[BM * BK];
  int b = blockIdx.y;
  int t = blockIdx.x;                 // 0..527 triangular
  int bi = 0;
  while (t >= NT - bi) { t -= NT - bi; ++bi; }
  int bj = bi + t;
  const ushort* X = nrm + (size_t)b * NROW * DDIM;
  int i0 = bi * BM, j0 = bj * BM;
  int tid  = threadIdx.x;
  int lane = tid & 63, wav = tid >> 6;
  int wr = wav >> 1, wc = wav & 1;

  f32x4 acc[4][4] = {};
  for (int kt = 0; kt < DDIM / BK; ++kt) {
    int k0 = kt * BK;
    #pragma unroll
    for (int s = 0; s < 4; ++s) {
      int flat = s * 256 + tid;       // 16B segment
      int idx  = flat * 8;            // elem index in tile
      int r = idx >> 6, k = idx & 63;
      GLDS16(X + (size_t)(i0 + r) * DDIM + k0 + k, &lA[idx]);
      GLDS16(X + (size_t)(j0 + r) * DDIM + k0 + k, &lB[idx]);
    }
    __syncthreads();
    bf16x8 fa[2][4], fb[2][4];
    #pragma unroll
    for (int kk = 0; kk < 2; ++kk) {
      int ko = kk * 32 + (lane >> 4) * 8;
      #pragma unroll
      for (int m = 0; m < 4; ++m) {
        int ra = wr * 64 + m * 16 + (lane & 15);
        fa[kk][m] = *(const bf16x8*)&lA[ra * BK + ko];
        int rb = wc * 64 + m * 16 + (lane & 15);
        fb[kk][m] = *(const bf16x8*)&lB[rb * BK + ko];
      }
    }
    #pragma unroll
    for (int kk = 0; kk < 2; ++kk)
      #pragma unroll
      for (int m = 0; m < 4; ++m)
        #pragma unroll
        for (int n = 0; n < 4; ++n)
          acc[m][n] = __builtin_amdgcn_mfma_f32_16x16x32_bf16(
              fa[kk][m], fb[kk][n], acc[m][n], 0, 0, 0);
    __syncthreads();
  }
  // epilogue: threshold, emit sparse entries (rare path)
  int qrb = (lane >> 4) * 4;
  int cl  = lane & 15;
  #pragma unroll
  for (int m = 0; m < 4; ++m)
    #pragma unroll
    for (int n = 0; n < 4; ++n)
      #pragma unroll
      for (int q = 0; q < 4; ++q) {
        float sim = acc[m][n][q];
        if (sim > SIM_T) {
          int rl = wr * 64 + m * 16 + qrb + q;
          int cc = wc * 64 + n * 16 + cl;
          if (bi != bj || cc > rl) {
            int i = i0 + rl, j = j0 + cc;
            int p = atomicAdd(&cnt[b], 2);
            if (p + 1 < CAP_E) {
              entI[b * CAP_E + p]     = i; entJ[b * CAP_E + p]     = j; entV[b * CAP_E + p]     = sim;
              entI[b * CAP_E + p + 1] = j; entJ[b * CAP_E + p + 1] = i; entV[b * CAP_E + p + 1] = sim;
            }
            touch_row(b, i, sim, flags, rowcnt, rowlist, rowsum);
            touch_row(b, j, sim, flags, rowcnt, rowlist, rowsum);
          }
        }
      }
}

// ---------------- stage 3-5: sparse FC layer ----------------
// u_i = (adj@h)[i] ; layer1: h=emb (dense read); layer>1: h = r_prev + d_prev
// D_cur[s] = relu(u_i @ W^T + bias) - relu(bias)
__global__ __launch_bounds__(256)
void fc_kernel(int layer,
               const float* __restrict__ emb,
               const float* __restrict__ Dprev, float* __restrict__ Dcur,
               const float* __restrict__ W, const float* __restrict__ bias,
               const float* __restrict__ biasPrev,
               const int* __restrict__ cnt, const int* __restrict__ rowcnt,
               const int* __restrict__ entI, const int* __restrict__ entJ,
               const float* __restrict__ entV,
               const int* __restrict__ flags, const int* __restrict__ rowlist,
               const float* __restrict__ rowsum) {
  __shared__ float u[DDIM];
  int b  = blockIdx.y;
  int rc = min(rowcnt[b], ROWCAP);
  int ec = min(cnt[b], CAP_E);
  for (int s = blockIdx.x; s < rc; s += gridDim.x) {
    int i  = rowlist[b * ROWCAP + s];
    int tt = threadIdx.x;
    float u0 = 0.f, u1 = 0.f, u2 = 0.f;
    if (layer > 1) {
      float rs = rowsum[b * NROW + i];
      u0 = rs * fmaxf(biasPrev[tt], 0.f);
      u1 = rs * fmaxf(biasPrev[tt + 256], 0.f);
      u2 = rs * fmaxf(biasPrev[tt + 512], 0.f);
    }
    for (int e = 0; e < ec; ++e) {
      if (entI[b * CAP_E + e] == i) {
        int   j = entJ[b * CAP_E + e];
        float v = entV[b * CAP_E + e];
        if (layer == 1) {
          const float* x = emb + ((size_t)b * NROW + j) * DDIM;
          u0 += v * x[tt]; u1 += v * x[tt + 256]; u2 += v * x[tt + 512];
        } else {
          int pos = flags[b * NROW + j];
          if (pos > 0) {
            const float* x = Dprev + ((size_t)b * ROWCAP + (pos - 1)) * DDIM;
            u0 += v * x[tt]; u1 += v * x[tt + 256]; u2 += v * x[tt + 512];
          }
        }
      }
    }
    u[tt] = u0; u[tt + 256] = u1; u[tt + 512] = u2;
    __syncthreads();
    #pragma unroll
    for (int kk = 0; kk < 3; ++kk) {
      int k = tt + kk * 256;
      const float* wrow = W + (size_t)k * DDIM;
      float a = bias[k];
      #pragma unroll 8
      for (int m = 0; m < DDIM; ++m) a += u[m] * wrow[m];
      float h = fmaxf(a, 0.f);
      Dcur[((size_t)b * ROWCAP + s) * DDIM + k] = h - fmaxf(bias[k], 0.f);
    }
    __syncthreads();
  }
}

// ---------------- stage 6: output mean ----------------
__global__ __launch_bounds__(256)
void out_kernel(const float* __restrict__ Dlast, const float* __restrict__ b3,
                const int* __restrict__ rowcnt, float* __restrict__ out) {
  int b = blockIdx.x, tt = threadIdx.x;
  int rc = min(rowcnt[b], ROWCAP);
  #pragma unroll
  for (int kk = 0; kk < 3; ++kk) {
    int k = tt + kk * 256;
    float a = 0.f;
    for (int s = 0; s < rc; ++s) a += Dlast[((size_t)b * ROWCAP + s) * DDIM + k];
    out[b * DDIM + k] = fmaxf(b3[k], 0.f) + a * (1.0f / (float)NROW);
  }
}

extern "C" void kernel_launch(void* const* d_in, const int* in_sizes, int n_in,
                              void* d_out, int out_size, void* d_ws, size_t ws_size,
                              hipStream_t stream) {
  (void)in_sizes; (void)n_in; (void)out_size; (void)ws_size;
  const float* emb = (const float*)d_in[0];
  const float* W1  = (const float*)d_in[1];
  const float* b1  = (const float*)d_in[2];
  const float* W2  = (const float*)d_in[3];
  const float* b2  = (const float*)d_in[4];
  const float* W3  = (const float*)d_in[5];
  const float* b3  = (const float*)d_in[6];
  float* out = (float*)d_out;

  char* w = (char*)d_ws;
  size_t off = 0;
  int*   cnt     = (int*)(w + off);   off += BDOC * 4;
  int*   rowcnt  = (int*)(w + off);   off += BDOC * 4;
  int*   flags   = (int*)(w + off);   off += (size_t)BDOC * NROW * 4;
  float* rowsum  = (float*)(w + off); off += (size_t)BDOC * NROW * 4;
  int*   entI    = (int*)(w + off);   off += (size_t)BDOC * CAP_E * 4;
  int*   entJ    = (int*)(w + off);   off += (size_t)BDOC * CAP_E * 4;
  float* entV    = (float*)(w + off); off += (size_t)BDOC * CAP_E * 4;
  size_t zbytes  = off;                       // everything above gets zeroed
  int*   rowlist = (int*)(w + off);   off += (size_t)BDOC * ROWCAP * 4;
  off = (off + 255) & ~(size_t)255;
  __hip_bfloat16* nrmbf = (__hip_bfloat16*)(w + off);
  off += (size_t)BDOC * NROW * DDIM * 2;
  float* D0 = (float*)(w + off); off += (size_t)BDOC * ROWCAP * DDIM * 4;
  float* D1 = (float*)(w + off); off += (size_t)BDOC * ROWCAP * DDIM * 4;

  hipMemsetAsync(w, 0, zbytes, stream);

  nrm_kernel<<<BDOC * NROW, 256, 0, stream>>>(emb, nrmbf);

  gram_kernel<<<dim3(NT * (NT + 1) / 2, BDOC), 256, 0, stream>>>(
      (const ushort*)nrmbf, cnt, rowcnt, entI, entJ, entV, flags, rowlist, rowsum);

  fc_kernel<<<dim3(16, BDOC), 256, 0, stream>>>(1, emb, D1, D0, W1, b1, b1,
      cnt, rowcnt, entI, entJ, entV, flags, rowlist, rowsum);
  fc_kernel<<<dim3(16, BDOC), 256, 0, stream>>>(2, emb, D0, D1, W2, b2, b1,
      cnt, rowcnt, entI, entJ, entV, flags, rowlist, rowsum);
  fc_kernel<<<dim3(16, BDOC), 256, 0, stream>>>(3, emb, D1, D0, W3, b3, b2,
      cnt, rowcnt, entI, entJ, entV, flags, rowlist, rowsum);

  out_kernel<<<BDOC, 256, 0, stream>>>(D0, b3, rowcnt, out);
}

// Round 3
// 424.408 us; speedup vs baseline: 1.0837x; 1.0837x over previous
//
#include <hip/hip_runtime.h>
#include <hip/hip_bf16.h>

#define BDOC 8
#define NROW 4096
#define DDIM 768
#define NT   32          // NROW / BM
#define BM   128
#define BK   64
#define CAP_E  8192
#define ROWCAP 512
#define SIM_T 0.2f

typedef __attribute__((ext_vector_type(8))) __bf16 bf16x8;
typedef __attribute__((ext_vector_type(4))) float  f32x4;

#define GLDS16(gptr, lptr) __builtin_amdgcn_global_load_lds( \
    (const __attribute__((address_space(1))) void*)(gptr),   \
    (__attribute__((address_space(3))) void*)(lptr), 16, 0, 0)

__device__ __forceinline__ ushort f2bf(float x) {
  return __builtin_bit_cast(ushort, __float2bfloat16(x));
}

// ---------------- stage 1: row norms + bf16 normalized copy ----------------
// one wave per row: float4 loads, shfl-only reduce, ushort4 bf16 stores
__global__ __launch_bounds__(256)
void nrm_kernel(const float* __restrict__ emb, ushort* __restrict__ nrmbf) {
  int gw   = (blockIdx.x * 256 + threadIdx.x) >> 6;   // global wave id = row
  int lane = threadIdx.x & 63;
  const float4* x = (const float4*)(emb + (size_t)gw * DDIM);
  float4 v[3];
  float ss = 0.f;
  #pragma unroll
  for (int q = 0; q < 3; ++q) {
    v[q] = x[lane + 64 * q];
    ss += v[q].x * v[q].x + v[q].y * v[q].y + v[q].z * v[q].z + v[q].w * v[q].w;
  }
  #pragma unroll
  for (int o = 32; o > 0; o >>= 1) ss += __shfl_xor(ss, o);
  float inv = 1.0f / fmaxf(sqrtf(ss), 1e-8f);
  ushort* o = nrmbf + (size_t)gw * DDIM;
  #pragma unroll
  for (int q = 0; q < 3; ++q) {
    ushort4 s;
    s.x = f2bf(v[q].x * inv);
    s.y = f2bf(v[q].y * inv);
    s.z = f2bf(v[q].z * inv);
    s.w = f2bf(v[q].w * inv);
    *(ushort4*)(o + lane * 4 + q * 256) = s;
  }
}

// ---------------- sparse bookkeeping ----------------
__device__ __forceinline__ void touch_row(int b, int i, float v,
    int* flags, int* rowcnt, int* rowlist, float* rowsum) {
  atomicAdd(&rowsum[b * NROW + i], v);
  if (atomicCAS(&flags[b * NROW + i], 0, (int)0x80000000) == 0) {
    int s = atomicAdd(&rowcnt[b], 1);
    if (s < ROWCAP) {
      rowlist[b * ROWCAP + s] = i;
      __threadfence();
      flags[b * NROW + i] = s + 1;
    }
  }
}

// ---------------- stage 2: Gram + threshold (MFMA bf16, upper triangle) ----
// LDS layout: 16B chunk (r, c) stored at chunk slot r*8 + (c ^ (r&7))
// (involutive XOR swizzle; global source pre-swizzled since global_load_lds
//  writes linearly — rule: linear dest + inverse-swz source + swz on read)
__global__ __launch_bounds__(256)
void gram_kernel(const ushort* __restrict__ nrm,
                 int* __restrict__ cnt, int* __restrict__ rowcnt,
                 int* __restrict__ entI, int* __restrict__ entJ, float* __restrict__ entV,
                 int* __restrict__ flags, int* __restrict__ rowlist,
                 float* __restrict__ rowsum) {
  __shared__ ushort lA[BM * BK];
  __shared__ ushort lB[BM * BK];
  int b = blockIdx.y;
  // XCD-aware swizzle: 528 tiles, 528 % 8 == 0 -> bijective chunked map
  int bidx = blockIdx.x;
  int t = (bidx & 7) * (NT * (NT + 1) / 2 / 8) + (bidx >> 3);
  int bi = 0;
  while (t >= NT - bi) { t -= NT - bi; ++bi; }
  int bj = bi + t;
  const ushort* X = nrm + (size_t)b * NROW * DDIM;
  int i0 = bi * BM, j0 = bj * BM;
  int tid  = threadIdx.x;
  int lane = tid & 63, wav = tid >> 6;
  int wr = wav >> 1, wc = wav & 1;

  f32x4 acc[4][4] = {};
  for (int kt = 0; kt < DDIM / BK; ++kt) {
    int k0 = kt * BK;
    #pragma unroll
    for (int s = 0; s < 4; ++s) {
      int flat = s * 256 + tid;       // 16B chunk slot in tile (linear dest)
      int r    = flat >> 3;           // row 0..127
      int cdst = flat & 7;            // dest chunk-col
      int csrc = cdst ^ (r & 7);      // pre-swizzled source chunk-col
      GLDS16(X + (size_t)(i0 + r) * DDIM + k0 + csrc * 8, &lA[flat * 8]);
      GLDS16(X + (size_t)(j0 + r) * DDIM + k0 + csrc * 8, &lB[flat * 8]);
    }
    __syncthreads();
    bf16x8 fa[2][4], fb[2][4];
    #pragma unroll
    for (int kk = 0; kk < 2; ++kk) {
      int ko = kk * 32 + (lane >> 4) * 8;
      #pragma unroll
      for (int m = 0; m < 4; ++m) {
        int ra = wr * 64 + m * 16 + (lane & 15);
        fa[kk][m] = *(const bf16x8*)&lA[ra * BK + (ko ^ ((ra & 7) << 3))];
        int rb = wc * 64 + m * 16 + (lane & 15);
        fb[kk][m] = *(const bf16x8*)&lB[rb * BK + (ko ^ ((rb & 7) << 3))];
      }
    }
    #pragma unroll
    for (int kk = 0; kk < 2; ++kk)
      #pragma unroll
      for (int m = 0; m < 4; ++m)
        #pragma unroll
        for (int n = 0; n < 4; ++n)
          acc[m][n] = __builtin_amdgcn_mfma_f32_16x16x32_bf16(
              fa[kk][m], fb[kk][n], acc[m][n], 0, 0, 0);
    __syncthreads();
  }
  // epilogue: threshold, emit sparse entries (rare path)
  int qrb = (lane >> 4) * 4;
  int cl  = lane & 15;
  #pragma unroll
  for (int m = 0; m < 4; ++m)
    #pragma unroll
    for (int n = 0; n < 4; ++n)
      #pragma unroll
      for (int q = 0; q < 4; ++q) {
        float sim = acc[m][n][q];
        if (sim > SIM_T) {
          int rl = wr * 64 + m * 16 + qrb + q;
          int cc = wc * 64 + n * 16 + cl;
          if (bi != bj || cc > rl) {
            int i = i0 + rl, j = j0 + cc;
            int p = atomicAdd(&cnt[b], 2);
            if (p + 1 < CAP_E) {
              entI[b * CAP_E + p]     = i; entJ[b * CAP_E + p]     = j; entV[b * CAP_E + p]     = sim;
              entI[b * CAP_E + p + 1] = j; entJ[b * CAP_E + p + 1] = i; entV[b * CAP_E + p + 1] = sim;
            }
            touch_row(b, i, sim, flags, rowcnt, rowlist, rowsum);
            touch_row(b, j, sim, flags, rowcnt, rowlist, rowsum);
          }
        }
      }
}

// ---------------- stage 3-5: sparse FC layer ----------------
__global__ __launch_bounds__(256)
void fc_kernel(int layer,
               const float* __restrict__ emb,
               const float* __restrict__ Dprev, float* __restrict__ Dcur,
               const float* __restrict__ W, const float* __restrict__ bias,
               const float* __restrict__ biasPrev,
               const int* __restrict__ cnt, const int* __restrict__ rowcnt,
               const int* __restrict__ entI, const int* __restrict__ entJ,
               const float* __restrict__ entV,
               const int* __restrict__ flags, const int* __restrict__ rowlist,
               const float* __restrict__ rowsum) {
  __shared__ float u[DDIM];
  int b  = blockIdx.y;
  int rc = min(rowcnt[b], ROWCAP);
  int ec = min(cnt[b], CAP_E);
  for (int s = blockIdx.x; s < rc; s += gridDim.x) {
    int i  = rowlist[b * ROWCAP + s];
    int tt = threadIdx.x;
    float u0 = 0.f, u1 = 0.f, u2 = 0.f;
    if (layer > 1) {
      float rs = rowsum[b * NROW + i];
      u0 = rs * fmaxf(biasPrev[tt], 0.f);
      u1 = rs * fmaxf(biasPrev[tt + 256], 0.f);
      u2 = rs * fmaxf(biasPrev[tt + 512], 0.f);
    }
    for (int e = 0; e < ec; ++e) {
      if (entI[b * CAP_E + e] == i) {
        int   j = entJ[b * CAP_E + e];
        float v = entV[b * CAP_E + e];
        if (layer == 1) {
          const float* x = emb + ((size_t)b * NROW + j) * DDIM;
          u0 += v * x[tt]; u1 += v * x[tt + 256]; u2 += v * x[tt + 512];
        } else {
          int pos = flags[b * NROW + j];
          if (pos > 0) {
            const float* x = Dprev + ((size_t)b * ROWCAP + (pos - 1)) * DDIM;
            u0 += v * x[tt]; u1 += v * x[tt + 256]; u2 += v * x[tt + 512];
          }
        }
      }
    }
    u[tt] = u0; u[tt + 256] = u1; u[tt + 512] = u2;
    __syncthreads();
    #pragma unroll
    for (int kk = 0; kk < 3; ++kk) {
      int k = tt + kk * 256;
      const float* wrow = W + (size_t)k * DDIM;
      float a = bias[k];
      #pragma unroll 8
      for (int m = 0; m < DDIM; ++m) a += u[m] * wrow[m];
      float h = fmaxf(a, 0.f);
      Dcur[((size_t)b * ROWCAP + s) * DDIM + k] = h - fmaxf(bias[k], 0.f);
    }
    __syncthreads();
  }
}

// ---------------- stage 6: output mean ----------------
__global__ __launch_bounds__(256)
void out_kernel(const float* __restrict__ Dlast, const float* __restrict__ b3,
                const int* __restrict__ rowcnt, float* __restrict__ out) {
  int b = blockIdx.x, tt = threadIdx.x;
  int rc = min(rowcnt[b], ROWCAP);
  #pragma unroll
  for (int kk = 0; kk < 3; ++kk) {
    int k = tt + kk * 256;
    float a = 0.f;
    for (int s = 0; s < rc; ++s) a += Dlast[((size_t)b * ROWCAP + s) * DDIM + k];
    out[b * DDIM + k] = fmaxf(b3[k], 0.f) + a * (1.0f / (float)NROW);
  }
}

extern "C" void kernel_launch(void* const* d_in, const int* in_sizes, int n_in,
                              void* d_out, int out_size, void* d_ws, size_t ws_size,
                              hipStream_t stream) {
  (void)in_sizes; (void)n_in; (void)out_size; (void)ws_size;
  const float* emb = (const float*)d_in[0];
  const float* W1  = (const float*)d_in[1];
  const float* b1  = (const float*)d_in[2];
  const float* W2  = (const float*)d_in[3];
  const float* b2  = (const float*)d_in[4];
  const float* W3  = (const float*)d_in[5];
  const float* b3  = (const float*)d_in[6];
  float* out = (float*)d_out;

  char* w = (char*)d_ws;
  size_t off = 0;
  int*   cnt     = (int*)(w + off);   off += BDOC * 4;
  int*   rowcnt  = (int*)(w + off);   off += BDOC * 4;
  int*   flags   = (int*)(w + off);   off += (size_t)BDOC * NROW * 4;
  float* rowsum  = (float*)(w + off); off += (size_t)BDOC * NROW * 4;
  int*   entI    = (int*)(w + off);   off += (size_t)BDOC * CAP_E * 4;
  int*   entJ    = (int*)(w + off);   off += (size_t)BDOC * CAP_E * 4;
  float* entV    = (float*)(w + off); off += (size_t)BDOC * CAP_E * 4;
  size_t zbytes  = off;                       // everything above gets zeroed
  int*   rowlist = (int*)(w + off);   off += (size_t)BDOC * ROWCAP * 4;
  off = (off + 255) & ~(size_t)255;
  ushort* nrmbf = (ushort*)(w + off);
  off += (size_t)BDOC * NROW * DDIM * 2;
  float* D0 = (float*)(w + off); off += (size_t)BDOC * ROWCAP * DDIM * 4;
  float* D1 = (float*)(w + off); off += (size_t)BDOC * ROWCAP * DDIM * 4;

  (void)hipMemsetAsync(w, 0, zbytes, stream);

  nrm_kernel<<<BDOC * NROW / 4, 256, 0, stream>>>(emb, nrmbf);

  gram_kernel<<<dim3(NT * (NT + 1) / 2, BDOC), 256, 0, stream>>>(
      nrmbf, cnt, rowcnt, entI, entJ, entV, flags, rowlist, rowsum);

  fc_kernel<<<dim3(16, BDOC), 256, 0, stream>>>(1, emb, D1, D0, W1, b1, b1,
      cnt, rowcnt, entI, entJ, entV, flags, rowlist, rowsum);
  fc_kernel<<<dim3(16, BDOC), 256, 0, stream>>>(2, emb, D0, D1, W2, b2, b1,
      cnt, rowcnt, entI, entJ, entV, flags, rowlist, rowsum);
  fc_kernel<<<dim3(16, BDOC), 256, 0, stream>>>(3, emb, D1, D0, W3, b3, b2,
      cnt, rowcnt, entI, entJ, entV, flags, rowlist, rowsum);

  out_kernel<<<BDOC, 256, 0, stream>>>(D0, b3, rowcnt, out);
}

// Round 4
// 197.873 us; speedup vs baseline: 2.3244x; 2.1449x over previous
//
#include <hip/hip_runtime.h>
#include <hip/hip_bf16.h>

#define BDOC 8
#define NROW 4096
#define DDIM 768
#define NT   32          // NROW / BM
#define BM   128
#define BK   64
#define CAP_E  8192
#define ROWCAP 512
#define SIM_T 0.2f
#define KCH  48          // fc k-chunks: 48 blocks x 16 outputs = 768

typedef __attribute__((ext_vector_type(8))) __bf16 bf16x8;
typedef __attribute__((ext_vector_type(4))) float  f32x4;

#define GLDS16(gptr, lptr) __builtin_amdgcn_global_load_lds( \
    (const __attribute__((address_space(1))) void*)(gptr),   \
    (__attribute__((address_space(3))) void*)(lptr), 16, 0, 0)

__device__ __forceinline__ ushort f2bf(float x) {
  return __builtin_bit_cast(ushort, __float2bfloat16(x));
}

// ---------------- stage 1: row norms + bf16 normalized copy ----------------
__global__ __launch_bounds__(256)
void nrm_kernel(const float* __restrict__ emb, ushort* __restrict__ nrmbf) {
  int gw   = (blockIdx.x * 256 + threadIdx.x) >> 6;   // global wave id = row
  int lane = threadIdx.x & 63;
  const float4* x = (const float4*)(emb + (size_t)gw * DDIM);
  float4 v[3];
  float ss = 0.f;
  #pragma unroll
  for (int q = 0; q < 3; ++q) {
    v[q] = x[lane + 64 * q];
    ss += v[q].x * v[q].x + v[q].y * v[q].y + v[q].z * v[q].z + v[q].w * v[q].w;
  }
  #pragma unroll
  for (int o = 32; o > 0; o >>= 1) ss += __shfl_xor(ss, o);
  float inv = 1.0f / fmaxf(sqrtf(ss), 1e-8f);
  ushort* o = nrmbf + (size_t)gw * DDIM;
  #pragma unroll
  for (int q = 0; q < 3; ++q) {
    ushort4 s;
    s.x = f2bf(v[q].x * inv);
    s.y = f2bf(v[q].y * inv);
    s.z = f2bf(v[q].z * inv);
    s.w = f2bf(v[q].w * inv);
    *(ushort4*)(o + lane * 4 + q * 256) = s;
  }
}

// ---------------- sparse bookkeeping ----------------
__device__ __forceinline__ void touch_row(int b, int i, float v,
    int* flags, int* rowcnt, int* rowlist, float* rowsum) {
  atomicAdd(&rowsum[b * NROW + i], v);
  if (atomicCAS(&flags[b * NROW + i], 0, (int)0x80000000) == 0) {
    int s = atomicAdd(&rowcnt[b], 1);
    if (s < ROWCAP) {
      rowlist[b * ROWCAP + s] = i;
      __threadfence();
      flags[b * NROW + i] = s + 1;
    }
  }
}

// ---------------- stage 2: Gram + threshold (MFMA bf16, upper triangle) ----
__global__ __launch_bounds__(256)
void gram_kernel(const ushort* __restrict__ nrm,
                 int* __restrict__ cnt, int* __restrict__ rowcnt,
                 int* __restrict__ entI, int* __restrict__ entJ, float* __restrict__ entV,
                 int* __restrict__ flags, int* __restrict__ rowlist,
                 float* __restrict__ rowsum) {
  __shared__ ushort lA[BM * BK];
  __shared__ ushort lB[BM * BK];
  int b = blockIdx.y;
  int bidx = blockIdx.x;
  int t = (bidx & 7) * (NT * (NT + 1) / 2 / 8) + (bidx >> 3);
  int bi = 0;
  while (t >= NT - bi) { t -= NT - bi; ++bi; }
  int bj = bi + t;
  const ushort* X = nrm + (size_t)b * NROW * DDIM;
  int i0 = bi * BM, j0 = bj * BM;
  int tid  = threadIdx.x;
  int lane = tid & 63, wav = tid >> 6;
  int wr = wav >> 1, wc = wav & 1;

  f32x4 acc[4][4] = {};
  for (int kt = 0; kt < DDIM / BK; ++kt) {
    int k0 = kt * BK;
    #pragma unroll
    for (int s = 0; s < 4; ++s) {
      int flat = s * 256 + tid;       // 16B chunk slot in tile (linear dest)
      int r    = flat >> 3;
      int cdst = flat & 7;
      int csrc = cdst ^ (r & 7);      // pre-swizzled source chunk-col
      GLDS16(X + (size_t)(i0 + r) * DDIM + k0 + csrc * 8, &lA[flat * 8]);
      GLDS16(X + (size_t)(j0 + r) * DDIM + k0 + csrc * 8, &lB[flat * 8]);
    }
    __syncthreads();
    bf16x8 fa[2][4], fb[2][4];
    #pragma unroll
    for (int kk = 0; kk < 2; ++kk) {
      int ko = kk * 32 + (lane >> 4) * 8;
      #pragma unroll
      for (int m = 0; m < 4; ++m) {
        int ra = wr * 64 + m * 16 + (lane & 15);
        fa[kk][m] = *(const bf16x8*)&lA[ra * BK + (ko ^ ((ra & 7) << 3))];
        int rb = wc * 64 + m * 16 + (lane & 15);
        fb[kk][m] = *(const bf16x8*)&lB[rb * BK + (ko ^ ((rb & 7) << 3))];
      }
    }
    #pragma unroll
    for (int kk = 0; kk < 2; ++kk)
      #pragma unroll
      for (int m = 0; m < 4; ++m)
        #pragma unroll
        for (int n = 0; n < 4; ++n)
          acc[m][n] = __builtin_amdgcn_mfma_f32_16x16x32_bf16(
              fa[kk][m], fb[kk][n], acc[m][n], 0, 0, 0);
    __syncthreads();
  }
  int qrb = (lane >> 4) * 4;
  int cl  = lane & 15;
  #pragma unroll
  for (int m = 0; m < 4; ++m)
    #pragma unroll
    for (int n = 0; n < 4; ++n)
      #pragma unroll
      for (int q = 0; q < 4; ++q) {
        float sim = acc[m][n][q];
        if (sim > SIM_T) {
          int rl = wr * 64 + m * 16 + qrb + q;
          int cc = wc * 64 + n * 16 + cl;
          if (bi != bj || cc > rl) {
            int i = i0 + rl, j = j0 + cc;
            int p = atomicAdd(&cnt[b], 2);
            if (p + 1 < CAP_E) {
              entI[b * CAP_E + p]     = i; entJ[b * CAP_E + p]     = j; entV[b * CAP_E + p]     = sim;
              entI[b * CAP_E + p + 1] = j; entJ[b * CAP_E + p + 1] = i; entV[b * CAP_E + p + 1] = sim;
            }
            touch_row(b, i, sim, flags, rowcnt, rowlist, rowsum);
            touch_row(b, j, sim, flags, rowcnt, rowlist, rowsum);
          }
        }
      }
}

// ---------------- stage 3-5: sparse FC layer (k-chunk parallel) ----------------
// grid (KCH, BDOC); block x computes outputs [x*16, x*16+16) for all active rows.
// W reads are coalesced float4 (16-lane group per output row) and spread over
// KCH CUs instead of one.
__global__ __launch_bounds__(256)
void fc_kernel(int layer,
               const float* __restrict__ emb,
               const float* __restrict__ Dprev, float* __restrict__ Dcur,
               const float* __restrict__ W, const float* __restrict__ bias,
               const float* __restrict__ biasPrev,
               const int* __restrict__ cnt, const int* __restrict__ rowcnt,
               const int* __restrict__ entI, const int* __restrict__ entJ,
               const float* __restrict__ entV,
               const int* __restrict__ flags, const int* __restrict__ rowlist,
               const float* __restrict__ rowsum) {
  __shared__ float u[DDIM];
  int b  = blockIdx.y;
  int rc = min(rowcnt[b], ROWCAP);
  int ec = min(cnt[b], CAP_E);
  if (rc == 0) return;
  int tid = threadIdx.x;
  int g   = tid >> 4;               // output group 0..15
  int t16 = tid & 15;
  int k   = blockIdx.x * 16 + g;    // this group's output index
  for (int s = 0; s < rc; ++s) {
    int i = rowlist[b * ROWCAP + s];
    // ---- cooperative u = (adj@h)[i] (3 elems/thread) ----
    float u0 = 0.f, u1 = 0.f, u2 = 0.f;
    if (layer > 1) {
      float rs = rowsum[b * NROW + i];
      u0 = rs * fmaxf(biasPrev[tid], 0.f);
      u1 = rs * fmaxf(biasPrev[tid + 256], 0.f);
      u2 = rs * fmaxf(biasPrev[tid + 512], 0.f);
    }
    for (int e = 0; e < ec; ++e) {
      if (entI[b * CAP_E + e] == i) {
        int   j = entJ[b * CAP_E + e];
        float v = entV[b * CAP_E + e];
        if (layer == 1) {
          const float* x = emb + ((size_t)b * NROW + j) * DDIM;
          u0 += v * x[tid]; u1 += v * x[tid + 256]; u2 += v * x[tid + 512];
        } else {
          int pos = flags[b * NROW + j];
          if (pos > 0) {
            const float* x = Dprev + ((size_t)b * ROWCAP + (pos - 1)) * DDIM;
            u0 += v * x[tid]; u1 += v * x[tid + 256]; u2 += v * x[tid + 512];
          }
        }
      }
    }
    u[tid] = u0; u[tid + 256] = u1; u[tid + 512] = u2;
    __syncthreads();
    // ---- out[k] = relu(u @ W[k,:] + bias[k]) - relu(bias[k]) ----
    const float4* wrow = (const float4*)(W + (size_t)k * DDIM);
    const float4* uv   = (const float4*)u;
    float a = 0.f;
    #pragma unroll
    for (int c = 0; c < DDIM / 4 / 16; ++c) {   // 12 iters
      float4 wv = wrow[t16 + c * 16];
      float4 um = uv[t16 + c * 16];
      a += wv.x * um.x + wv.y * um.y + wv.z * um.z + wv.w * um.w;
    }
    #pragma unroll
    for (int o = 8; o > 0; o >>= 1) a += __shfl_xor(a, o);
    if (t16 == 0) {
      float h = fmaxf(a + bias[k], 0.f);
      Dcur[((size_t)b * ROWCAP + s) * DDIM + k] = h - fmaxf(bias[k], 0.f);
    }
    __syncthreads();
  }
}

// ---------------- stage 6: output mean ----------------
__global__ __launch_bounds__(256)
void out_kernel(const float* __restrict__ Dlast, const float* __restrict__ b3,
                const int* __restrict__ rowcnt, float* __restrict__ out) {
  int b = blockIdx.x, tt = threadIdx.x;
  int rc = min(rowcnt[b], ROWCAP);
  #pragma unroll
  for (int kk = 0; kk < 3; ++kk) {
    int k = tt + kk * 256;
    float a = 0.f;
    for (int s = 0; s < rc; ++s) a += Dlast[((size_t)b * ROWCAP + s) * DDIM + k];
    out[b * DDIM + k] = fmaxf(b3[k], 0.f) + a * (1.0f / (float)NROW);
  }
}

extern "C" void kernel_launch(void* const* d_in, const int* in_sizes, int n_in,
                              void* d_out, int out_size, void* d_ws, size_t ws_size,
                              hipStream_t stream) {
  (void)in_sizes; (void)n_in; (void)out_size; (void)ws_size;
  const float* emb = (const float*)d_in[0];
  const float* W1  = (const float*)d_in[1];
  const float* b1  = (const float*)d_in[2];
  const float* W2  = (const float*)d_in[3];
  const float* b2  = (const float*)d_in[4];
  const float* W3  = (const float*)d_in[5];
  const float* b3  = (const float*)d_in[6];
  float* out = (float*)d_out;

  char* w = (char*)d_ws;
  size_t off = 0;
  int*   cnt     = (int*)(w + off);   off += BDOC * 4;
  int*   rowcnt  = (int*)(w + off);   off += BDOC * 4;
  int*   flags   = (int*)(w + off);   off += (size_t)BDOC * NROW * 4;
  float* rowsum  = (float*)(w + off); off += (size_t)BDOC * NROW * 4;
  int*   entI    = (int*)(w + off);   off += (size_t)BDOC * CAP_E * 4;
  int*   entJ    = (int*)(w + off);   off += (size_t)BDOC * CAP_E * 4;
  float* entV    = (float*)(w + off); off += (size_t)BDOC * CAP_E * 4;
  size_t zbytes  = off;                       // everything above gets zeroed
  int*   rowlist = (int*)(w + off);   off += (size_t)BDOC * ROWCAP * 4;
  off = (off + 255) & ~(size_t)255;
  ushort* nrmbf = (ushort*)(w + off);
  off += (size_t)BDOC * NROW * DDIM * 2;
  float* D0 = (float*)(w + off); off += (size_t)BDOC * ROWCAP * DDIM * 4;
  float* D1 = (float*)(w + off); off += (size_t)BDOC * ROWCAP * DDIM * 4;

  (void)hipMemsetAsync(w, 0, zbytes, stream);

  nrm_kernel<<<BDOC * NROW / 4, 256, 0, stream>>>(emb, nrmbf);

  gram_kernel<<<dim3(NT * (NT + 1) / 2, BDOC), 256, 0, stream>>>(
      nrmbf, cnt, rowcnt, entI, entJ, entV, flags, rowlist, rowsum);

  fc_kernel<<<dim3(KCH, BDOC), 256, 0, stream>>>(1, emb, D1, D0, W1, b1, b1,
      cnt, rowcnt, entI, entJ, entV, flags, rowlist, rowsum);
  fc_kernel<<<dim3(KCH, BDOC), 256, 0, stream>>>(2, emb, D0, D1, W2, b2, b1,
      cnt, rowcnt, entI, entJ, entV, flags, rowlist, rowsum);
  fc_kernel<<<dim3(KCH, BDOC), 256, 0, stream>>>(3, emb, D1, D0, W3, b3, b2,
      cnt, rowcnt, entI, entJ, entV, flags, rowlist, rowsum);

  out_kernel<<<BDOC, 256, 0, stream>>>(D0, b3, rowcnt, out);
}

// Round 5
// 168.429 us; speedup vs baseline: 2.7307x; 1.1748x over previous
//
#include <hip/hip_runtime.h>
#include <hip/hip_bf16.h>

#define BDOC 8
#define NROW 4096
#define DDIM 768
#define NT   32          // NROW / BM
#define BM   128
#define BK   64
#define CAP_E  8192
#define ROWCAP 512
#define SIM_T 0.2f
#define KCH  48          // fc k-chunks: 48 blocks x 16 outputs = 768

typedef __attribute__((ext_vector_type(8))) __bf16 bf16x8;
typedef __attribute__((ext_vector_type(4))) float  f32x4;

#define GLDS16(gptr, lptr) __builtin_amdgcn_global_load_lds( \
    (const __attribute__((address_space(1))) void*)(gptr),   \
    (__attribute__((address_space(3))) void*)(lptr), 16, 0, 0)

__device__ __forceinline__ ushort f2bf(float x) {
  return __builtin_bit_cast(ushort, __float2bfloat16(x));
}

// ---------------- stage 1: row norms + bf16 normalized copy ----------------
__global__ __launch_bounds__(256)
void nrm_kernel(const float* __restrict__ emb, ushort* __restrict__ nrmbf) {
  int gw   = (blockIdx.x * 256 + threadIdx.x) >> 6;   // global wave id = row
  int lane = threadIdx.x & 63;
  const float4* x = (const float4*)(emb + (size_t)gw * DDIM);
  float4 v[3];
  float ss = 0.f;
  #pragma unroll
  for (int q = 0; q < 3; ++q) {
    v[q] = x[lane + 64 * q];
    ss += v[q].x * v[q].x + v[q].y * v[q].y + v[q].z * v[q].z + v[q].w * v[q].w;
  }
  #pragma unroll
  for (int o = 32; o > 0; o >>= 1) ss += __shfl_xor(ss, o);
  float inv = 1.0f / fmaxf(sqrtf(ss), 1e-8f);
  ushort* o = nrmbf + (size_t)gw * DDIM;
  #pragma unroll
  for (int q = 0; q < 3; ++q) {
    ushort4 s;
    s.x = f2bf(v[q].x * inv);
    s.y = f2bf(v[q].y * inv);
    s.z = f2bf(v[q].z * inv);
    s.w = f2bf(v[q].w * inv);
    *(ushort4*)(o + lane * 4 + q * 256) = s;
  }
}

// ---------------- sparse bookkeeping ----------------
__device__ __forceinline__ void touch_row(int b, int i, float v,
    int* flags, int* rowcnt, int* rowlist, float* rowsum) {
  atomicAdd(&rowsum[b * NROW + i], v);
  if (atomicCAS(&flags[b * NROW + i], 0, (int)0x80000000) == 0) {
    int s = atomicAdd(&rowcnt[b], 1);
    if (s < ROWCAP) {
      rowlist[b * ROWCAP + s] = i;
      __threadfence();
      flags[b * NROW + i] = s + 1;
    }
  }
}

// ---------------- stage 2: Gram + threshold (MFMA bf16, upper triangle) ----
// All staging + fragment addresses hoisted out of the K-loop:
//  - staging: csrc is s-invariant (rows step by 32 == 0 mod 8) -> 8 pointers
//    advanced by +BK per K-step; LDS dests are compile-time constants.
//  - fragments: swizzled ko(kk=1) == ko(kk=0)^32 -> 4 invariant base
//    pointers + imm offsets m*2048B.
//  - diagonal tiles (bi==bj): skip B staging, read B-fragments from lA.
__global__ __launch_bounds__(256)
void gram_kernel(const ushort* __restrict__ nrm,
                 int* __restrict__ cnt, int* __restrict__ rowcnt,
                 int* __restrict__ entI, int* __restrict__ entJ, float* __restrict__ entV,
                 int* __restrict__ flags, int* __restrict__ rowlist,
                 float* __restrict__ rowsum) {
  __shared__ ushort lA[BM * BK];
  __shared__ ushort lB[BM * BK];
  int b = blockIdx.y;
  int bidx = blockIdx.x;
  int t = (bidx & 7) * (NT * (NT + 1) / 2 / 8) + (bidx >> 3);
  int bi = 0;
  while (t >= NT - bi) { t -= NT - bi; ++bi; }
  int bj = bi + t;
  bool diag = (bi == bj);
  const ushort* X = nrm + (size_t)b * NROW * DDIM;
  int i0 = bi * BM, j0 = bj * BM;
  int tid  = threadIdx.x;
  int lane = tid & 63, wav = tid >> 6;
  int wr = wav >> 1, wc = wav & 1;

  // ---- hoisted staging addresses ----
  int r0 = tid >> 3;                       // row within 32-row stripe
  int c0 = (tid & 7) ^ (r0 & 7);           // pre-swizzled source chunk-col
  const ushort* ga0 = X + (size_t)(i0 + r0) * DDIM + c0 * 8;
  const ushort* ga1 = ga0 + (size_t)32 * DDIM;
  const ushort* ga2 = ga0 + (size_t)64 * DDIM;
  const ushort* ga3 = ga0 + (size_t)96 * DDIM;
  const ushort* gb0 = X + (size_t)(j0 + r0) * DDIM + c0 * 8;
  const ushort* gb1 = gb0 + (size_t)32 * DDIM;
  const ushort* gb2 = gb0 + (size_t)64 * DDIM;
  const ushort* gb3 = gb0 + (size_t)96 * DDIM;
  int l0 = tid * 8, l1 = (256 + tid) * 8, l2 = (512 + tid) * 8, l3 = (768 + tid) * 8;

  // ---- hoisted fragment read pointers ----
  int lanelo = lane & 15;
  int ko0 = ((lane >> 4) * 8) ^ ((lane & 7) << 3);
  const ushort* lBp = diag ? lA : lB;
  const ushort* pa0 = &lA [(wr * 64 + lanelo) * BK + ko0];
  const ushort* pa1 = &lA [(wr * 64 + lanelo) * BK + (ko0 ^ 32)];
  const ushort* pb0 = &lBp[(wc * 64 + lanelo) * BK + ko0];
  const ushort* pb1 = &lBp[(wc * 64 + lanelo) * BK + (ko0 ^ 32)];

  f32x4 acc[4][4] = {};
  for (int kt = 0; kt < DDIM / BK; ++kt) {
    GLDS16(ga0, &lA[l0]); GLDS16(ga1, &lA[l1]);
    GLDS16(ga2, &lA[l2]); GLDS16(ga3, &lA[l3]);
    if (!diag) {
      GLDS16(gb0, &lB[l0]); GLDS16(gb1, &lB[l1]);
      GLDS16(gb2, &lB[l2]); GLDS16(gb3, &lB[l3]);
    }
    ga0 += BK; ga1 += BK; ga2 += BK; ga3 += BK;
    gb0 += BK; gb1 += BK; gb2 += BK; gb3 += BK;
    __syncthreads();
    bf16x8 fa[2][4], fb[2][4];
    #pragma unroll
    for (int m = 0; m < 4; ++m) {
      fa[0][m] = *(const bf16x8*)(pa0 + m * 16 * BK);
      fa[1][m] = *(const bf16x8*)(pa1 + m * 16 * BK);
      fb[0][m] = *(const bf16x8*)(pb0 + m * 16 * BK);
      fb[1][m] = *(const bf16x8*)(pb1 + m * 16 * BK);
    }
    #pragma unroll
    for (int kk = 0; kk < 2; ++kk)
      #pragma unroll
      for (int m = 0; m < 4; ++m)
        #pragma unroll
        for (int n = 0; n < 4; ++n)
          acc[m][n] = __builtin_amdgcn_mfma_f32_16x16x32_bf16(
              fa[kk][m], fb[kk][n], acc[m][n], 0, 0, 0);
    __syncthreads();
  }
  int qrb = (lane >> 4) * 4;
  int cl  = lane & 15;
  #pragma unroll
  for (int m = 0; m < 4; ++m)
    #pragma unroll
    for (int n = 0; n < 4; ++n)
      #pragma unroll
      for (int q = 0; q < 4; ++q) {
        float sim = acc[m][n][q];
        if (sim > SIM_T) {
          int rl = wr * 64 + m * 16 + qrb + q;
          int cc = wc * 64 + n * 16 + cl;
          if (bi != bj || cc > rl) {
            int i = i0 + rl, j = j0 + cc;
            int p = atomicAdd(&cnt[b], 2);
            if (p + 1 < CAP_E) {
              entI[b * CAP_E + p]     = i; entJ[b * CAP_E + p]     = j; entV[b * CAP_E + p]     = sim;
              entI[b * CAP_E + p + 1] = j; entJ[b * CAP_E + p + 1] = i; entV[b * CAP_E + p + 1] = sim;
            }
            touch_row(b, i, sim, flags, rowcnt, rowlist, rowsum);
            touch_row(b, j, sim, flags, rowcnt, rowlist, rowsum);
          }
        }
      }
}

// ---------------- stage 3-5: sparse FC layer (k-chunk parallel) ----------------
__global__ __launch_bounds__(256)
void fc_kernel(int layer,
               const float* __restrict__ emb,
               const float* __restrict__ Dprev, float* __restrict__ Dcur,
               const float* __restrict__ W, const float* __restrict__ bias,
               const float* __restrict__ biasPrev,
               const int* __restrict__ cnt, const int* __restrict__ rowcnt,
               const int* __restrict__ entI, const int* __restrict__ entJ,
               const float* __restrict__ entV,
               const int* __restrict__ flags, const int* __restrict__ rowlist,
               const float* __restrict__ rowsum) {
  __shared__ float u[DDIM];
  int b  = blockIdx.y;
  int rc = min(rowcnt[b], ROWCAP);
  int ec = min(cnt[b], CAP_E);
  if (rc == 0) return;
  int tid = threadIdx.x;
  int g   = tid >> 4;               // output group 0..15
  int t16 = tid & 15;
  int k   = blockIdx.x * 16 + g;    // this group's output index
  for (int s = 0; s < rc; ++s) {
    int i = rowlist[b * ROWCAP + s];
    float u0 = 0.f, u1 = 0.f, u2 = 0.f;
    if (layer > 1) {
      float rs = rowsum[b * NROW + i];
      u0 = rs * fmaxf(biasPrev[tid], 0.f);
      u1 = rs * fmaxf(biasPrev[tid + 256], 0.f);
      u2 = rs * fmaxf(biasPrev[tid + 512], 0.f);
    }
    for (int e = 0; e < ec; ++e) {
      if (entI[b * CAP_E + e] == i) {
        int   j = entJ[b * CAP_E + e];
        float v = entV[b * CAP_E + e];
        if (layer == 1) {
          const float* x = emb + ((size_t)b * NROW + j) * DDIM;
          u0 += v * x[tid]; u1 += v * x[tid + 256]; u2 += v * x[tid + 512];
        } else {
          int pos = flags[b * NROW + j];
          if (pos > 0) {
            const float* x = Dprev + ((size_t)b * ROWCAP + (pos - 1)) * DDIM;
            u0 += v * x[tid]; u1 += v * x[tid + 256]; u2 += v * x[tid + 512];
          }
        }
      }
    }
    u[tid] = u0; u[tid + 256] = u1; u[tid + 512] = u2;
    __syncthreads();
    const float4* wrow = (const float4*)(W + (size_t)k * DDIM);
    const float4* uv   = (const float4*)u;
    float a = 0.f;
    #pragma unroll
    for (int c = 0; c < DDIM / 4 / 16; ++c) {   // 12 iters
      float4 wv = wrow[t16 + c * 16];
      float4 um = uv[t16 + c * 16];
      a += wv.x * um.x + wv.y * um.y + wv.z * um.z + wv.w * um.w;
    }
    #pragma unroll
    for (int o = 8; o > 0; o >>= 1) a += __shfl_xor(a, o);
    if (t16 == 0) {
      float h = fmaxf(a + bias[k], 0.f);
      Dcur[((size_t)b * ROWCAP + s) * DDIM + k] = h - fmaxf(bias[k], 0.f);
    }
    __syncthreads();
  }
}

// ---------------- stage 6: output mean ----------------
__global__ __launch_bounds__(256)
void out_kernel(const float* __restrict__ Dlast, const float* __restrict__ b3,
                const int* __restrict__ rowcnt, float* __restrict__ out) {
  int b = blockIdx.x, tt = threadIdx.x;
  int rc = min(rowcnt[b], ROWCAP);
  #pragma unroll
  for (int kk = 0; kk < 3; ++kk) {
    int k = tt + kk * 256;
    float a = 0.f;
    for (int s = 0; s < rc; ++s) a += Dlast[((size_t)b * ROWCAP + s) * DDIM + k];
    out[b * DDIM + k] = fmaxf(b3[k], 0.f) + a * (1.0f / (float)NROW);
  }
}

extern "C" void kernel_launch(void* const* d_in, const int* in_sizes, int n_in,
                              void* d_out, int out_size, void* d_ws, size_t ws_size,
                              hipStream_t stream) {
  (void)in_sizes; (void)n_in; (void)out_size; (void)ws_size;
  const float* emb = (const float*)d_in[0];
  const float* W1  = (const float*)d_in[1];
  const float* b1  = (const float*)d_in[2];
  const float* W2  = (const float*)d_in[3];
  const float* b2  = (const float*)d_in[4];
  const float* W3  = (const float*)d_in[5];
  const float* b3  = (const float*)d_in[6];
  float* out = (float*)d_out;

  char* w = (char*)d_ws;
  size_t off = 0;
  int*   cnt     = (int*)(w + off);   off += BDOC * 4;
  int*   rowcnt  = (int*)(w + off);   off += BDOC * 4;
  int*   flags   = (int*)(w + off);   off += (size_t)BDOC * NROW * 4;
  float* rowsum  = (float*)(w + off); off += (size_t)BDOC * NROW * 4;
  int*   entI    = (int*)(w + off);   off += (size_t)BDOC * CAP_E * 4;
  int*   entJ    = (int*)(w + off);   off += (size_t)BDOC * CAP_E * 4;
  float* entV    = (float*)(w + off); off += (size_t)BDOC * CAP_E * 4;
  size_t zbytes  = off;                       // everything above gets zeroed
  int*   rowlist = (int*)(w + off);   off += (size_t)BDOC * ROWCAP * 4;
  off = (off + 255) & ~(size_t)255;
  ushort* nrmbf = (ushort*)(w + off);
  off += (size_t)BDOC * NROW * DDIM * 2;
  float* D0 = (float*)(w + off); off += (size_t)BDOC * ROWCAP * DDIM * 4;
  float* D1 = (float*)(w + off); off += (size_t)BDOC * ROWCAP * DDIM * 4;

  (void)hipMemsetAsync(w, 0, zbytes, stream);

  nrm_kernel<<<BDOC * NROW / 4, 256, 0, stream>>>(emb, nrmbf);

  gram_kernel<<<dim3(NT * (NT + 1) / 2, BDOC), 256, 0, stream>>>(
      nrmbf, cnt, rowcnt, entI, entJ, entV, flags, rowlist, rowsum);

  fc_kernel<<<dim3(KCH, BDOC), 256, 0, stream>>>(1, emb, D1, D0, W1, b1, b1,
      cnt, rowcnt, entI, entJ, entV, flags, rowlist, rowsum);
  fc_kernel<<<dim3(KCH, BDOC), 256, 0, stream>>>(2, emb, D0, D1, W2, b2, b1,
      cnt, rowcnt, entI, entJ, entV, flags, rowlist, rowsum);
  fc_kernel<<<dim3(KCH, BDOC), 256, 0, stream>>>(3, emb, D1, D0, W3, b3, b2,
      cnt, rowcnt, entI, entJ, entV, flags, rowlist, rowsum);

  out_kernel<<<BDOC, 256, 0, stream>>>(D0, b3, rowcnt, out);
}